// Round 6
// baseline (275.431 us; speedup 1.0000x reference)
//
#include <hip/hip_runtime.h>

// NaryDecoderCell: B=2048, C=256, HS=512, H2=1024, D=8
// pack(bf16, gate-interleaved B) -> mega_gemm (K=1280, 2-phase K-tiles,
//   fused GRU epilogue) -> split-K gemm_bt(hc) -> reduce+tanh -> h
//   probs via atomics + final sigmoid

#define B_   2048
#define C_   256
#define HS_  512
#define H2_  1024
#define G3_  3072
#define D_   8
#define NG_  24576
#define KF_  1280

typedef __attribute__((ext_vector_type(8))) short bfrag;     // 8 x bf16
typedef __attribute__((ext_vector_type(4))) float f32x4;     // MFMA C/D
typedef __attribute__((ext_vector_type(4))) unsigned short u16x4;
typedef __attribute__((ext_vector_type(2))) unsigned int u32x2;

static __device__ __forceinline__ unsigned short f2bf(float f) {
  unsigned u = __float_as_uint(f);
  u = (u + 0x7FFFu + ((u >> 16) & 1u)) >> 16;   // RTNE
  return (unsigned short)u;
}
static __device__ __forceinline__ float bf2f(unsigned short s) {
  return __uint_as_float(((unsigned)s) << 16);
}
static __device__ __forceinline__ unsigned pack2bf(float a, float b) {
  return ((unsigned)f2bf(b) << 16) | (unsigned)f2bf(a);
}
static __device__ __forceinline__ float fast_sigmoid(float x) {
  return 1.f / (1.f + __expf(-x));
}
static __device__ __forceinline__ float fast_tanh(float x) {
  return 1.f - 2.f / (__expf(2.f * x) + 1.f);
}

__device__ __forceinline__ void load16(const void* g, void* l) {
  __builtin_amdgcn_global_load_lds((const __attribute__((address_space(1))) void*)g,
                                   (__attribute__((address_space(3))) void*)l,
                                   16, 0, 0);
}

// ---------------- pack: f32 -> bf16 ----------------
// A  [2048][1280] = [x(256) | ph(512) | enc(512)]
// Bf [24576][1280], rows gate-interleaved: p = d*3072 + hb*192 + g*64 + hl
// BWh[512][8192]   = W_h permuted: Bt[kk][d*1024+h]
__global__ __launch_bounds__(256) void pack_kernel(
    const float* __restrict__ x, const float* __restrict__ ph,
    const float* __restrict__ enc, const float* __restrict__ Wih,
    const float* __restrict__ Whh, const float* __restrict__ Wh,
    unsigned short* __restrict__ A, unsigned short* __restrict__ Bf,
    unsigned short* __restrict__ BWh)
{
  const long long total4 = 38273024LL / 4;
  const long long stride = (long long)gridDim.x * blockDim.x;
  for (long long i = (long long)blockIdx.x * blockDim.x + threadIdx.x;
       i < total4; i += stride) {
    long long o = i * 4;
    const float* src;
    unsigned short* dst;
    if (o < 2621440) {                       // A
      unsigned rel = (unsigned)o;
      unsigned b = rel / 1280u, c = rel % 1280u;
      if (c < 256) src = x + (size_t)b * 256 + c;
      else if (c < 768) src = ph + (size_t)b * 512 + (c - 256);
      else src = enc + (size_t)b * 512 + (c - 768);
      dst = A + rel;
    } else if (o < 34078720) {               // Bf gate-interleaved
      unsigned rel = (unsigned)(o - 2621440);
      unsigned grow = rel / 1280u, c = rel % 1280u;
      unsigned d = grow / 3072u, rr = grow - d * 3072u;
      unsigned hbb = rr / 192u, r3 = rr - hbb * 192u;
      unsigned g = r3 >> 6, hl = r3 & 63u;
      unsigned srow = d * 3072u + g * 1024u + hbb * 64u + hl;
      src = (c < 256) ? (Wih + (size_t)srow * 256 + c)
                      : (Whh + (size_t)srow * 1024 + (c - 256));
      dst = Bf + rel;
    } else {                                 // BWh permute
      unsigned rel = (unsigned)(o - 34078720);
      unsigned kk = rel >> 13;
      unsigned r2 = rel & 8191;
      unsigned d = r2 >> 10, hh = r2 & 1023;
      src = Wh + ((size_t)d * 524288 + (size_t)kk * 1024 + hh);
      dst = BWh + rel;
    }
    float4 v = *(const float4*)src;
    ushort4 w;
    w.x = f2bf(v.x); w.y = f2bf(v.y); w.z = f2bf(v.z); w.w = f2bf(v.w);
    *(ushort4*)dst = w;
  }
}

// ---------------- mega GEMM: 256x192 tile, K=1280, fused GRU epilogue ------
// 8 waves (2M x 4N-of-48cols), BK=64, TWO phases per K-tile (24 MFMA each),
// distance-2 prefetch, vmcnt(7) per tile. LDS: A [0,65536) 2buf;
// B [65536,114688) 2buf; in_lds [114688,147968).
__global__ __launch_bounds__(512, 2) void mega_gemm(
    const unsigned short* __restrict__ A, const unsigned short* __restrict__ Bf,
    const float* __restrict__ ph, const float* __restrict__ enc,
    const float* __restrict__ bih, const float* __restrict__ bhh,
    const float* __restrict__ Wp, unsigned short* __restrict__ hn,
    float* __restrict__ pacc)
{
  extern __shared__ char lds[];
  const int t = threadIdx.x;
  const int wave = t >> 6, lane = t & 63;
  const int wr = wave >> 2, wc = wave & 3;
  const int la = lane & 15, ls = lane >> 4;

  // T1 bijective XCD swizzle (nwg=1024), column-major decode (8 row-blocks)
  const int q8 = gridDim.x >> 3;
  const int orig = blockIdx.x;
  const int swz = (orig & 7) * q8 + (orig >> 3);
  const int brow = (swz & 7) << 8;
  const int cb = swz >> 3;                   // 0..127
  const int bcol = cb * 192;
  const int d = cb >> 4, hb = cb & 15;
  const int nT = 20;

  const int srr = t >> 3;
  const int ssc = ((t & 7) ^ ((t >> 3) & 7)) << 3;   // pre-swizzled src col

  auto stageA = [&](int kt, int buf, int hf) {
    const unsigned short* src = A + (size_t)(brow + hf * 128 + srr) * KF_ + kt * 64 + ssc;
    char* dst = lds + buf * 32768 + hf * 16384 + t * 16;
    load16(src, dst);
    load16(src + (size_t)64 * KF_, dst + 8192);
  };
  auto stageB = [&](int kt, int buf, int th) {
    const unsigned short* src = Bf + (size_t)(bcol + th * 64 + srr) * KF_ + kt * 64 + ssc;
    char* dst = lds + 65536 + buf * 24576 + th * 8192 + t * 16;
    load16(src, dst);
  };

  // prologue: tile0 (7 loads) then tile1 (7 loads); drain tile0 only
  stageA(0, 0, 0); stageA(0, 0, 1);
  stageB(0, 0, 0); stageB(0, 0, 1); stageB(0, 0, 2);
  stageA(1, 1, 0); stageA(1, 1, 1);
  stageB(1, 1, 0); stageB(1, 1, 1); stageB(1, 1, 2);
  asm volatile("s_waitcnt vmcnt(7)" ::: "memory");
  __builtin_amdgcn_s_barrier();

  f32x4 acc[8][3];
#pragma unroll
  for (int m = 0; m < 8; ++m)
#pragma unroll
    for (int n = 0; n < 3; ++n) acc[m][n] = (f32x4){0.f, 0.f, 0.f, 0.f};

  const int c0 = (ls << 4) ^ ((la & 7) << 4);        // swizzled k0 byte col

#pragma unroll 1
  for (int kt = 0; kt < nT; ++kt) {
    const int buf = kt & 1;
    const char* ab = lds + buf * 32768 + wr * 16384;
    const char* bb = lds + 65536 + buf * 24576;
    bfrag a0[8], a1[8], b0[3], b1[3];

    // ---- P1: read the whole tile (k0 operands first); MFMA k0 (24)
#pragma unroll
    for (int m = 0; m < 8; ++m)
      a0[m] = *(const bfrag*)(ab + (m * 16 + la) * 128 + c0);
#pragma unroll
    for (int n = 0; n < 3; ++n) {
      const int r = wc * 48 + n * 16 + la;
      b0[n] = *(const bfrag*)(bb + (r >> 6) * 8192 + (r & 63) * 128 + c0);
    }
#pragma unroll
    for (int m = 0; m < 8; ++m)
      a1[m] = *(const bfrag*)(ab + (m * 16 + la) * 128 + (c0 ^ 64));
#pragma unroll
    for (int n = 0; n < 3; ++n) {
      const int r = wc * 48 + n * 16 + la;
      b1[n] = *(const bfrag*)(bb + (r >> 6) * 8192 + (r & 63) * 128 + (c0 ^ 64));
    }
    __builtin_amdgcn_s_barrier();
    __builtin_amdgcn_s_setprio(1);
#pragma unroll
    for (int m = 0; m < 8; ++m)
#pragma unroll
      for (int n = 0; n < 3; ++n)
        acc[m][n] = __builtin_amdgcn_mfma_f32_16x16x32_bf16(a0[m], b0[n], acc[m][n], 0, 0, 0);
    __builtin_amdgcn_s_setprio(0);
    asm volatile("s_waitcnt lgkmcnt(0)" ::: "memory");  // all tile reads done
    __builtin_amdgcn_s_barrier();

    // ---- P2: stage tile kt+2 into current buf; MFMA k1 (24, pure-register)
    if (kt + 2 < nT) {
      stageA(kt + 2, buf, 0);
      stageA(kt + 2, buf, 1);
      stageB(kt + 2, buf, 0);
      stageB(kt + 2, buf, 1);
      stageB(kt + 2, buf, 2);
    }
    __builtin_amdgcn_s_setprio(1);
#pragma unroll
    for (int m = 0; m < 8; ++m)
#pragma unroll
      for (int n = 0; n < 3; ++n)
        acc[m][n] = __builtin_amdgcn_mfma_f32_16x16x32_bf16(a1[m], b1[n], acc[m][n], 0, 0, 0);
    __builtin_amdgcn_s_setprio(0);
    if (kt + 2 < nT) {
      asm volatile("s_waitcnt vmcnt(7)" ::: "memory");  // tile kt+1 loads done
    } else {
      asm volatile("s_waitcnt vmcnt(0)" ::: "memory");
    }
    __builtin_amdgcn_s_barrier();

    // ---- K=256 boundary: n-gate frags snapshot i_n -> in_lds, reset acc
    if (kt == 3) {
#pragma unroll
      for (int m = 0; m < 8; ++m)
#pragma unroll
        for (int n = 0; n < 3; ++n) {
          const int colb = wc * 48 + n * 16;
          if (colb >= 128) {                           // wave-uniform per n
            const int hl = (colb & 63) + la;
            const int row = wr * 128 + m * 16 + ls * 4;
            u32x2 v;
            v[0] = pack2bf(acc[m][n][0], acc[m][n][1]);
            v[1] = pack2bf(acc[m][n][2], acc[m][n][3]);
            *(u32x2*)(lds + 114688 + hl * 520 + row * 2) = v;
            acc[m][n] = (f32x4){0.f, 0.f, 0.f, 0.f};
          }
        }
    }
  }

  // =================== fused GRU epilogue ===================
  __syncthreads();
#pragma unroll
  for (int m = 0; m < 8; ++m)
#pragma unroll
    for (int n = 0; n < 3; ++n) {
      const int col = wc * 48 + n * 16 + la;
      const int row = wr * 128 + m * 16 + ls * 4;
      u32x2 v;
      v[0] = pack2bf(acc[m][n][0], acc[m][n][1]);
      v[1] = pack2bf(acc[m][n][2], acc[m][n][3]);
      *(u32x2*)(lds + col * 520 + row * 2) = v;
    }
  __syncthreads();

  const unsigned short* lu = (const unsigned short*)lds;
  const int row = t >> 1, half = t & 1;
  const int grow = brow + row;
  const int hbase = hb * 64 + half * 32;
  const float* h0p = (hb < 8) ? (ph + (size_t)grow * 512 + hbase)
                              : (enc + (size_t)grow * 512 + hbase - 512);
  float partial = 0.f;
  u16x4 st;
#pragma unroll
  for (int jj = 0; jj < 8; ++jj) {
    const int hg = hbase + jj * 4;
    const f32x4 br_ = *(const f32x4*)(bih + d * 3072 + hg);
    const f32x4 hr_ = *(const f32x4*)(bhh + d * 3072 + hg);
    const f32x4 bz_ = *(const f32x4*)(bih + d * 3072 + 1024 + hg);
    const f32x4 hz_ = *(const f32x4*)(bhh + d * 3072 + 1024 + hg);
    const f32x4 bn_ = *(const f32x4*)(bih + d * 3072 + 2048 + hg);
    const f32x4 hn_ = *(const f32x4*)(bhh + d * 3072 + 2048 + hg);
    const f32x4 wp_ = *(const f32x4*)(Wp + d * 1024 + hg);
    const f32x4 h0_ = *(const f32x4*)(h0p + jj * 4);
#pragma unroll
    for (int i = 0; i < 4; ++i) {
      const int hl = half * 32 + jj * 4 + i;
      const float rp = bf2f(lu[hl * 260 + row]);
      const float zp = bf2f(lu[(64 + hl) * 260 + row]);
      const float sp = bf2f(lu[(128 + hl) * 260 + row]);
      const float ip = bf2f(lu[57344 + hl * 260 + row]);
      const float r = fast_sigmoid(rp + br_[i] + hr_[i]);
      const float z = fast_sigmoid(zp + bz_[i] + hz_[i]);
      const float nn = fast_tanh(ip + bn_[i] + r * (sp + hn_[i]));
      const float hv = (1.f - z) * nn + z * h0_[i];
      st[i] = f2bf(hv);
      partial += hv * wp_[i];
    }
    *(u16x4*)(hn + (size_t)grow * 8192 + d * 1024 + hg) = st;
  }
  partial += __shfl_xor(partial, 1);
  if (!half) atomicAdd(pacc + (size_t)grow * 8 + d, partial);
}

// ---------------- 128x128 GEMM (m97 structure) — split-K hc ----------------
__global__ __launch_bounds__(256) void gemm_bt(
    const unsigned short* __restrict__ A, const unsigned short* __restrict__ Bt,
    float* __restrict__ out, int M, int N, int K, int kPerSlice)
{
  __shared__ unsigned short sA[128 * 32];
  __shared__ unsigned short sB[128 * 32];
  const int t = threadIdx.x;
  const int wave = t >> 6, lane = t & 63;
  const int wr = wave >> 1, wc = wave & 1;
  const int brow = blockIdx.y << 7;
  const int bcol = blockIdx.x << 7;
  const int kOff = blockIdx.z * kPerSlice;

  f32x4 acc[4][4];
#pragma unroll
  for (int m = 0; m < 4; m++)
#pragma unroll
    for (int n = 0; n < 4; n++) acc[m][n] = (f32x4){0.f, 0.f, 0.f, 0.f};

  const int srow = t >> 2;
  const int scol = (t & 3) << 3;
  const unsigned short* aSrc = A + (size_t)(brow + srow) * K + kOff + scol;
  const unsigned short* bSrc = Bt + (size_t)(bcol + srow) * K + kOff + scol;
  const size_t rowStep = (size_t)64 * K;
  unsigned short* dA0 = sA + wave * 512;
  unsigned short* dA1 = sA + 2048 + wave * 512;
  unsigned short* dB0 = sB + wave * 512;
  unsigned short* dB1 = sB + 2048 + wave * 512;

  const int la = lane & 15;
  const int lk = (lane >> 4) << 3;
  const int kSteps = kPerSlice >> 5;

  for (int ks = 0; ks < kSteps; ++ks) {
    load16(aSrc, dA0);
    load16(aSrc + rowStep, dA1);
    load16(bSrc, dB0);
    load16(bSrc + rowStep, dB1);
    aSrc += 32; bSrc += 32;
    __syncthreads();
    bfrag aF[4], bF[4];
#pragma unroll
    for (int m = 0; m < 4; m++)
      aF[m] = *(const bfrag*)&sA[(wr * 64 + m * 16 + la) * 32 + lk];
#pragma unroll
    for (int n = 0; n < 4; n++)
      bF[n] = *(const bfrag*)&sB[(wc * 64 + n * 16 + la) * 32 + lk];
#pragma unroll
    for (int m = 0; m < 4; m++)
#pragma unroll
      for (int n = 0; n < 4; n++)
        acc[m][n] = __builtin_amdgcn_mfma_f32_16x16x32_bf16(aF[m], bF[n], acc[m][n], 0, 0, 0);
    __syncthreads();
  }

  const int orow = brow + wr * 64 + (lane >> 4) * 4;
  const int ocol = bcol + wc * 64 + la;
  float* o = out + (size_t)blockIdx.z * ((size_t)M * N);
#pragma unroll
  for (int m = 0; m < 4; m++) {
    const int rb = orow + m * 16;
#pragma unroll
    for (int n = 0; n < 4; n++) {
      const int cb = ocol + n * 16;
#pragma unroll
      for (int r = 0; r < 4; r++)
        o[(size_t)(rb + r) * N + cb] = acc[m][n][r];
    }
  }
}

// ---------------- reduce split-K partials + bias + tanh -> h ----------------
__global__ __launch_bounds__(256) void reduce_h_kernel(
    const float* __restrict__ part, const float* __restrict__ b_h,
    float* __restrict__ hout)
{
  const int idx = blockIdx.x * 256 + threadIdx.x;
  const int kk = idx & 511;
  float s = 0.f;
#pragma unroll
  for (int sl = 0; sl < 16; ++sl) s += part[(size_t)sl * 1048576 + idx];
  float bias = 0.f;
#pragma unroll
  for (int d = 0; d < 8; ++d) bias += b_h[d * 512 + kk];
  hout[idx] = fast_tanh(s + bias);
}

// ---------------- probs finalize: sigmoid(acc + b_p) ----------------
__global__ __launch_bounds__(256) void probs_final(
    const float* __restrict__ pacc, const float* __restrict__ b_p,
    float* __restrict__ pout)
{
  const int i = blockIdx.x * 256 + threadIdx.x;   // 16384 total
  pout[i] = fast_sigmoid(pacc[i] + b_p[i & 7]);
}

extern "C" void kernel_launch(void* const* d_in, const int* in_sizes, int n_in,
                              void* d_out, int out_size, void* d_ws, size_t ws_size,
                              hipStream_t stream) {
  const float* x   = (const float*)d_in[0];
  const float* ph  = (const float*)d_in[1];
  const float* enc = (const float*)d_in[2];
  const float* Wih = (const float*)d_in[3];
  const float* Whh = (const float*)d_in[4];
  const float* bih = (const float*)d_in[5];
  const float* bhh = (const float*)d_in[6];
  const float* Wp  = (const float*)d_in[7];
  const float* bp  = (const float*)d_in[8];
  const float* Wh  = (const float*)d_in[9];
  const float* bh  = (const float*)d_in[10];
  float* out = (float*)d_out;
  char* ws = (char*)d_ws;

  unsigned short* A    = (unsigned short*)(ws + 0);           //  5.24 MB
  unsigned short* Bf   = (unsigned short*)(ws + 5242880);     // 62.91 MB
  unsigned short* BWh  = (unsigned short*)(ws + 68157440);    //  8.39 MB
  unsigned short* hn   = (unsigned short*)(ws + 76546048);    // 33.55 MB
  float*          part = (float*)(ws + 110100480);            // 67.11 MB (16 slices)
  float*          pacc = (float*)(ws + 177209344);            // 64 KB

  hipFuncSetAttribute((const void*)mega_gemm,
                      hipFuncAttributeMaxDynamicSharedMemorySize, 147968);

  hipMemsetAsync(pacc, 0, 2048 * 8 * sizeof(float), stream);

  pack_kernel<<<2048, 256, 0, stream>>>(x, ph, enc, Wih, Whh, Wh, A, Bf, BWh);

  mega_gemm<<<1024, 512, 147968, stream>>>(A, Bf, ph, enc, bih, bhh, Wp, hn, pacc);

  dim3 g3(HS_ / 128, B_ / 128, 16);
  gemm_bt<<<g3, 256, 0, stream>>>(hn, BWh, part, B_, HS_, 8192, 512);

  reduce_h_kernel<<<4096, 256, 0, stream>>>(part, bh, out);

  probs_final<<<64, 256, 0, stream>>>(pacc, bp, out + 1048576);
}

// Round 7
// 265.386 us; speedup vs baseline: 1.0378x; 1.0378x over previous
//
#include <hip/hip_runtime.h>

// NaryDecoderCell: B=2048, C=256, HS=512, H2=1024, D=8
// pack(bf16, gate-interleaved B) -> mega_gemm (K=1280, 2-phase K-tiles,
//   XCD-affine brow/cb map, fused GRU epilogue) -> split-K gemm_bt(hc)
//   -> reduce+tanh -> h ; probs via atomics + final sigmoid

#define B_   2048
#define C_   256
#define HS_  512
#define H2_  1024
#define G3_  3072
#define D_   8
#define NG_  24576
#define KF_  1280

typedef __attribute__((ext_vector_type(8))) short bfrag;     // 8 x bf16
typedef __attribute__((ext_vector_type(4))) float f32x4;     // MFMA C/D
typedef __attribute__((ext_vector_type(4))) unsigned short u16x4;
typedef __attribute__((ext_vector_type(2))) unsigned int u32x2;

static __device__ __forceinline__ unsigned short f2bf(float f) {
  unsigned u = __float_as_uint(f);
  u = (u + 0x7FFFu + ((u >> 16) & 1u)) >> 16;   // RTNE
  return (unsigned short)u;
}
static __device__ __forceinline__ float bf2f(unsigned short s) {
  return __uint_as_float(((unsigned)s) << 16);
}
static __device__ __forceinline__ unsigned pack2bf(float a, float b) {
  return ((unsigned)f2bf(b) << 16) | (unsigned)f2bf(a);
}
static __device__ __forceinline__ float fast_sigmoid(float x) {
  return 1.f / (1.f + __expf(-x));
}
static __device__ __forceinline__ float fast_tanh(float x) {
  return 1.f - 2.f / (__expf(2.f * x) + 1.f);
}

__device__ __forceinline__ void load16(const void* g, void* l) {
  __builtin_amdgcn_global_load_lds((const __attribute__((address_space(1))) void*)g,
                                   (__attribute__((address_space(3))) void*)l,
                                   16, 0, 0);
}

// ---------------- pack: f32 -> bf16 ----------------
// A  [2048][1280] = [x(256) | ph(512) | enc(512)]
// Bf [24576][1280], rows gate-interleaved: p = d*3072 + hb*192 + g*64 + hl
// BWh[512][8192]   = W_h permuted: Bt[kk][d*1024+h]
__global__ __launch_bounds__(256) void pack_kernel(
    const float* __restrict__ x, const float* __restrict__ ph,
    const float* __restrict__ enc, const float* __restrict__ Wih,
    const float* __restrict__ Whh, const float* __restrict__ Wh,
    unsigned short* __restrict__ A, unsigned short* __restrict__ Bf,
    unsigned short* __restrict__ BWh)
{
  const long long total4 = 38273024LL / 4;
  const long long stride = (long long)gridDim.x * blockDim.x;
  for (long long i = (long long)blockIdx.x * blockDim.x + threadIdx.x;
       i < total4; i += stride) {
    long long o = i * 4;
    const float* src;
    unsigned short* dst;
    if (o < 2621440) {                       // A
      unsigned rel = (unsigned)o;
      unsigned b = rel / 1280u, c = rel % 1280u;
      if (c < 256) src = x + (size_t)b * 256 + c;
      else if (c < 768) src = ph + (size_t)b * 512 + (c - 256);
      else src = enc + (size_t)b * 512 + (c - 768);
      dst = A + rel;
    } else if (o < 34078720) {               // Bf gate-interleaved
      unsigned rel = (unsigned)(o - 2621440);
      unsigned grow = rel / 1280u, c = rel % 1280u;
      unsigned d = grow / 3072u, rr = grow - d * 3072u;
      unsigned hbb = rr / 192u, r3 = rr - hbb * 192u;
      unsigned g = r3 >> 6, hl = r3 & 63u;
      unsigned srow = d * 3072u + g * 1024u + hbb * 64u + hl;
      src = (c < 256) ? (Wih + (size_t)srow * 256 + c)
                      : (Whh + (size_t)srow * 1024 + (c - 256));
      dst = Bf + rel;
    } else {                                 // BWh permute
      unsigned rel = (unsigned)(o - 34078720);
      unsigned kk = rel >> 13;
      unsigned r2 = rel & 8191;
      unsigned d = r2 >> 10, hh = r2 & 1023;
      src = Wh + ((size_t)d * 524288 + (size_t)kk * 1024 + hh);
      dst = BWh + rel;
    }
    float4 v = *(const float4*)src;
    ushort4 w;
    w.x = f2bf(v.x); w.y = f2bf(v.y); w.z = f2bf(v.z); w.w = f2bf(v.w);
    *(ushort4*)dst = w;
  }
}

// ---------------- mega GEMM: 256x192 tile, K=1280, fused GRU epilogue ------
// 8 waves (2M x 4N-of-48cols), BK=64, two phases per K-tile, distance-2
// prefetch, vmcnt(7) per tile. XCD-affine map: XCD x -> 4 brows (A slices
// L2-resident), cb = 4k + (x>>1); 4 brows of a cb adjacent in time.
__global__ __launch_bounds__(512, 2) void mega_gemm(
    const unsigned short* __restrict__ A, const unsigned short* __restrict__ Bf,
    const float* __restrict__ ph, const float* __restrict__ enc,
    const float* __restrict__ bih, const float* __restrict__ bhh,
    const float* __restrict__ Wp, unsigned short* __restrict__ hn,
    float* __restrict__ pacc)
{
  extern __shared__ char lds[];
  const int t = threadIdx.x;
  const int wave = t >> 6, lane = t & 63;
  const int wr = wave >> 2, wc = wave & 3;
  const int la = lane & 15, ls = lane >> 4;

  // XCD-affine bijective map (1024 blocks; orig&7 ~ XCD heuristic)
  const int orig = blockIdx.x;
  const int xcd = orig & 7;
  const int l = orig >> 3;                   // 0..127 local to XCD
  const int brow8 = (xcd & 1) * 4 + (l & 3); // 4 brows per XCD
  const int cb = ((l >> 2) << 2) + (xcd >> 1);  // cb % 4 fixed per XCD
  const int brow = brow8 << 8;
  const int bcol = cb * 192;
  const int d = cb >> 4, hb = cb & 15;
  const int nT = 20;

  const int srr = t >> 3;
  const int ssc = ((t & 7) ^ ((t >> 3) & 7)) << 3;   // pre-swizzled src col

  auto stageA = [&](int kt, int buf, int hf) {
    const unsigned short* src = A + (size_t)(brow + hf * 128 + srr) * KF_ + kt * 64 + ssc;
    char* dst = lds + buf * 32768 + hf * 16384 + t * 16;
    load16(src, dst);
    load16(src + (size_t)64 * KF_, dst + 8192);
  };
  auto stageB = [&](int kt, int buf, int th) {
    const unsigned short* src = Bf + (size_t)(bcol + th * 64 + srr) * KF_ + kt * 64 + ssc;
    char* dst = lds + 65536 + buf * 24576 + th * 8192 + t * 16;
    load16(src, dst);
  };

  // prologue: tile0 (7 loads) then tile1 (7 loads); drain tile0 only
  stageA(0, 0, 0); stageA(0, 0, 1);
  stageB(0, 0, 0); stageB(0, 0, 1); stageB(0, 0, 2);
  stageA(1, 1, 0); stageA(1, 1, 1);
  stageB(1, 1, 0); stageB(1, 1, 1); stageB(1, 1, 2);
  asm volatile("s_waitcnt vmcnt(7)" ::: "memory");
  __builtin_amdgcn_s_barrier();

  f32x4 acc[8][3];
#pragma unroll
  for (int m = 0; m < 8; ++m)
#pragma unroll
    for (int n = 0; n < 3; ++n) acc[m][n] = (f32x4){0.f, 0.f, 0.f, 0.f};

  const int c0 = (ls << 4) ^ ((la & 7) << 4);        // swizzled k0 byte col

#pragma unroll 1
  for (int kt = 0; kt < nT; ++kt) {
    const int buf = kt & 1;
    const char* ab = lds + buf * 32768 + wr * 16384;
    const char* bb = lds + 65536 + buf * 24576;
    bfrag a0[8], a1[8], b0[3], b1[3];

    // ---- P1: read the whole tile (k0 operands first); MFMA k0 (24)
#pragma unroll
    for (int m = 0; m < 8; ++m)
      a0[m] = *(const bfrag*)(ab + (m * 16 + la) * 128 + c0);
#pragma unroll
    for (int n = 0; n < 3; ++n) {
      const int r = wc * 48 + n * 16 + la;
      b0[n] = *(const bfrag*)(bb + (r >> 6) * 8192 + (r & 63) * 128 + c0);
    }
#pragma unroll
    for (int m = 0; m < 8; ++m)
      a1[m] = *(const bfrag*)(ab + (m * 16 + la) * 128 + (c0 ^ 64));
#pragma unroll
    for (int n = 0; n < 3; ++n) {
      const int r = wc * 48 + n * 16 + la;
      b1[n] = *(const bfrag*)(bb + (r >> 6) * 8192 + (r & 63) * 128 + (c0 ^ 64));
    }
    __builtin_amdgcn_s_barrier();
    __builtin_amdgcn_s_setprio(1);
#pragma unroll
    for (int m = 0; m < 8; ++m)
#pragma unroll
      for (int n = 0; n < 3; ++n)
        acc[m][n] = __builtin_amdgcn_mfma_f32_16x16x32_bf16(a0[m], b0[n], acc[m][n], 0, 0, 0);
    __builtin_amdgcn_s_setprio(0);
    asm volatile("s_waitcnt lgkmcnt(0)" ::: "memory");  // all tile reads done
    __builtin_amdgcn_s_barrier();

    // ---- P2: stage tile kt+2 into current buf; MFMA k1 (24, pure-register)
    if (kt + 2 < nT) {
      stageA(kt + 2, buf, 0);
      stageA(kt + 2, buf, 1);
      stageB(kt + 2, buf, 0);
      stageB(kt + 2, buf, 1);
      stageB(kt + 2, buf, 2);
    }
    __builtin_amdgcn_s_setprio(1);
#pragma unroll
    for (int m = 0; m < 8; ++m)
#pragma unroll
      for (int n = 0; n < 3; ++n)
        acc[m][n] = __builtin_amdgcn_mfma_f32_16x16x32_bf16(a1[m], b1[n], acc[m][n], 0, 0, 0);
    __builtin_amdgcn_s_setprio(0);
    if (kt + 2 < nT) {
      asm volatile("s_waitcnt vmcnt(7)" ::: "memory");  // tile kt+1 loads done
    } else {
      asm volatile("s_waitcnt vmcnt(0)" ::: "memory");
    }
    __builtin_amdgcn_s_barrier();

    // ---- K=256 boundary: n-gate frags snapshot i_n -> in_lds, reset acc
    if (kt == 3) {
#pragma unroll
      for (int m = 0; m < 8; ++m)
#pragma unroll
        for (int n = 0; n < 3; ++n) {
          const int colb = wc * 48 + n * 16;
          if (colb >= 128) {                           // wave-uniform per n
            const int hl = (colb & 63) + la;
            const int row = wr * 128 + m * 16 + ls * 4;
            u32x2 v;
            v[0] = pack2bf(acc[m][n][0], acc[m][n][1]);
            v[1] = pack2bf(acc[m][n][2], acc[m][n][3]);
            *(u32x2*)(lds + 114688 + hl * 520 + row * 2) = v;
            acc[m][n] = (f32x4){0.f, 0.f, 0.f, 0.f};
          }
        }
    }
  }

  // =================== fused GRU epilogue ===================
  __syncthreads();
#pragma unroll
  for (int m = 0; m < 8; ++m)
#pragma unroll
    for (int n = 0; n < 3; ++n) {
      const int col = wc * 48 + n * 16 + la;
      const int row = wr * 128 + m * 16 + ls * 4;
      u32x2 v;
      v[0] = pack2bf(acc[m][n][0], acc[m][n][1]);
      v[1] = pack2bf(acc[m][n][2], acc[m][n][3]);
      *(u32x2*)(lds + col * 520 + row * 2) = v;
    }
  __syncthreads();

  const unsigned short* lu = (const unsigned short*)lds;
  const int row = t >> 1, half = t & 1;
  const int grow = brow + row;
  const int hbase = hb * 64 + half * 32;
  const float* h0p = (hb < 8) ? (ph + (size_t)grow * 512 + hbase)
                              : (enc + (size_t)grow * 512 + hbase - 512);
  float partial = 0.f;
  u16x4 st;
#pragma unroll
  for (int jj = 0; jj < 8; ++jj) {
    const int hg = hbase + jj * 4;
    const f32x4 br_ = *(const f32x4*)(bih + d * 3072 + hg);
    const f32x4 hr_ = *(const f32x4*)(bhh + d * 3072 + hg);
    const f32x4 bz_ = *(const f32x4*)(bih + d * 3072 + 1024 + hg);
    const f32x4 hz_ = *(const f32x4*)(bhh + d * 3072 + 1024 + hg);
    const f32x4 bn_ = *(const f32x4*)(bih + d * 3072 + 2048 + hg);
    const f32x4 hn_ = *(const f32x4*)(bhh + d * 3072 + 2048 + hg);
    const f32x4 wp_ = *(const f32x4*)(Wp + d * 1024 + hg);
    const f32x4 h0_ = *(const f32x4*)(h0p + jj * 4);
#pragma unroll
    for (int i = 0; i < 4; ++i) {
      const int hl = half * 32 + jj * 4 + i;
      const float rp = bf2f(lu[hl * 260 + row]);
      const float zp = bf2f(lu[(64 + hl) * 260 + row]);
      const float sp = bf2f(lu[(128 + hl) * 260 + row]);
      const float ip = bf2f(lu[57344 + hl * 260 + row]);
      const float r = fast_sigmoid(rp + br_[i] + hr_[i]);
      const float z = fast_sigmoid(zp + bz_[i] + hz_[i]);
      const float nn = fast_tanh(ip + bn_[i] + r * (sp + hn_[i]));
      const float hv = (1.f - z) * nn + z * h0_[i];
      st[i] = f2bf(hv);
      partial += hv * wp_[i];
    }
    *(u16x4*)(hn + (size_t)grow * 8192 + d * 1024 + hg) = st;
  }
  partial += __shfl_xor(partial, 1);
  if (!half) atomicAdd(pacc + (size_t)grow * 8 + d, partial);
}

// ---------------- 128x128 GEMM (m97 structure) — split-K hc ----------------
// XCD-affine: XCD owns a y-pair (A slices), B panels L2-shared per XCD.
__global__ __launch_bounds__(256) void gemm_bt(
    const unsigned short* __restrict__ A, const unsigned short* __restrict__ Bt,
    float* __restrict__ out, int M, int N, int K, int kPerSlice)
{
  __shared__ unsigned short sA[128 * 32];
  __shared__ unsigned short sB[128 * 32];
  const int t = threadIdx.x;
  const int wave = t >> 6, lane = t & 63;
  const int wr = wave >> 1, wc = wave & 1;

  // bijective decode of 1024 linear blocks -> (y in 0..15, xcol in 0..3, z in 0..15)
  const int orig = blockIdx.x;
  const int x7 = orig & 7;
  const int y = (x7 << 1) | ((orig >> 3) & 1);
  const int l2 = orig >> 4;
  const int xcol = l2 & 3;
  const int z = l2 >> 2;
  const int brow = y << 7;
  const int bcol = xcol << 7;
  const int kOff = z * kPerSlice;

  f32x4 acc[4][4];
#pragma unroll
  for (int m = 0; m < 4; m++)
#pragma unroll
    for (int n = 0; n < 4; n++) acc[m][n] = (f32x4){0.f, 0.f, 0.f, 0.f};

  const int srow = t >> 2;
  const int scol = (t & 3) << 3;
  const unsigned short* aSrc = A + (size_t)(brow + srow) * K + kOff + scol;
  const unsigned short* bSrc = Bt + (size_t)(bcol + srow) * K + kOff + scol;
  const size_t rowStep = (size_t)64 * K;
  unsigned short* dA0 = sA + wave * 512;
  unsigned short* dA1 = sA + 2048 + wave * 512;
  unsigned short* dB0 = sB + wave * 512;
  unsigned short* dB1 = sB + 2048 + wave * 512;

  const int la = lane & 15;
  const int lk = (lane >> 4) << 3;
  const int kSteps = kPerSlice >> 5;

  for (int ks = 0; ks < kSteps; ++ks) {
    load16(aSrc, dA0);
    load16(aSrc + rowStep, dA1);
    load16(bSrc, dB0);
    load16(bSrc + rowStep, dB1);
    aSrc += 32; bSrc += 32;
    __syncthreads();
    bfrag aF[4], bF[4];
#pragma unroll
    for (int m = 0; m < 4; m++)
      aF[m] = *(const bfrag*)&sA[(wr * 64 + m * 16 + la) * 32 + lk];
#pragma unroll
    for (int n = 0; n < 4; n++)
      bF[n] = *(const bfrag*)&sB[(wc * 64 + n * 16 + la) * 32 + lk];
#pragma unroll
    for (int m = 0; m < 4; m++)
#pragma unroll
      for (int n = 0; n < 4; n++)
        acc[m][n] = __builtin_amdgcn_mfma_f32_16x16x32_bf16(aF[m], bF[n], acc[m][n], 0, 0, 0);
    __syncthreads();
  }

  const int orow = brow + wr * 64 + (lane >> 4) * 4;
  const int ocol = bcol + wc * 64 + la;
  float* o = out + (size_t)z * ((size_t)M * N);
#pragma unroll
  for (int m = 0; m < 4; m++) {
    const int rb = orow + m * 16;
#pragma unroll
    for (int n = 0; n < 4; n++) {
      const int cbb = ocol + n * 16;
#pragma unroll
      for (int r = 0; r < 4; r++)
        o[(size_t)(rb + r) * N + cbb] = acc[m][n][r];
    }
  }
}

// ---------------- reduce split-K partials + bias + tanh -> h ----------------
__global__ __launch_bounds__(256) void reduce_h_kernel(
    const float* __restrict__ part, const float* __restrict__ b_h,
    float* __restrict__ hout)
{
  const int idx = blockIdx.x * 256 + threadIdx.x;
  const int kk = idx & 511;
  float s = 0.f;
#pragma unroll
  for (int sl = 0; sl < 16; ++sl) s += part[(size_t)sl * 1048576 + idx];
  float bias = 0.f;
#pragma unroll
  for (int d = 0; d < 8; ++d) bias += b_h[d * 512 + kk];
  hout[idx] = fast_tanh(s + bias);
}

// ---------------- probs finalize: sigmoid(acc + b_p) ----------------
__global__ __launch_bounds__(256) void probs_final(
    const float* __restrict__ pacc, const float* __restrict__ b_p,
    float* __restrict__ pout)
{
  const int i = blockIdx.x * 256 + threadIdx.x;   // 16384 total
  pout[i] = fast_sigmoid(pacc[i] + b_p[i & 7]);
}

extern "C" void kernel_launch(void* const* d_in, const int* in_sizes, int n_in,
                              void* d_out, int out_size, void* d_ws, size_t ws_size,
                              hipStream_t stream) {
  const float* x   = (const float*)d_in[0];
  const float* ph  = (const float*)d_in[1];
  const float* enc = (const float*)d_in[2];
  const float* Wih = (const float*)d_in[3];
  const float* Whh = (const float*)d_in[4];
  const float* bih = (const float*)d_in[5];
  const float* bhh = (const float*)d_in[6];
  const float* Wp  = (const float*)d_in[7];
  const float* bp  = (const float*)d_in[8];
  const float* Wh  = (const float*)d_in[9];
  const float* bh  = (const float*)d_in[10];
  float* out = (float*)d_out;
  char* ws = (char*)d_ws;

  unsigned short* A    = (unsigned short*)(ws + 0);           //  5.24 MB
  unsigned short* Bf   = (unsigned short*)(ws + 5242880);     // 62.91 MB
  unsigned short* BWh  = (unsigned short*)(ws + 68157440);    //  8.39 MB
  unsigned short* hn   = (unsigned short*)(ws + 76546048);    // 33.55 MB
  float*          part = (float*)(ws + 110100480);            // 67.11 MB (16 slices)
  float*          pacc = (float*)(ws + 177209344);            // 64 KB

  hipFuncSetAttribute((const void*)mega_gemm,
                      hipFuncAttributeMaxDynamicSharedMemorySize, 147968);

  hipMemsetAsync(pacc, 0, 2048 * 8 * sizeof(float), stream);

  pack_kernel<<<2048, 256, 0, stream>>>(x, ph, enc, Wih, Whh, Wh, A, Bf, BWh);

  mega_gemm<<<1024, 512, 147968, stream>>>(A, Bf, ph, enc, bih, bhh, Wp, hn, pacc);

  gemm_bt<<<1024, 256, 0, stream>>>(hn, BWh, part, B_, HS_, 8192, 512);

  reduce_h_kernel<<<4096, 256, 0, stream>>>(part, bh, out);

  probs_final<<<64, 256, 0, stream>>>(pacc, bp, out + 1048576);
}